// Round 6
// baseline (102.398 us; speedup 1.0000x reference)
//
#include <hip/hip_runtime.h>

constexpr int Tn = 512;       // seq len
constexpr int Bn = 4096;      // batch
constexpr int CH = 32;        // timesteps per chunk
constexpr int NCH = Tn / CH;  // 16

// Gates are computed PRE-SCALED by folding these into weights/biases:
// i,f,o by -log2e (sigmoid), g by +2*log2e (tanh). Cell state c is kept
// scaled by +2*log2e so tanh(c) needs no multiply on the critical path.
constexpr float NL2E = -1.44269504088896340736f;
constexpr float P2L2E = 2.88539008177792681472f;

#if defined(__has_builtin)
#if __has_builtin(__builtin_amdgcn_exp2f)
#define EXP2F(x) __builtin_amdgcn_exp2f(x)
#else
#define EXP2F(x) exp2f(x)
#endif
#else
#define EXP2F(x) exp2f(x)
#endif

// row_shr:1 within 16-lane rows: dst[i] = src[i-1]; lane0 of row keeps old.
__device__ __forceinline__ float dpp_shr1(float v) {
  return __int_as_float(__builtin_amdgcn_update_dpp(
      __float_as_int(v), __float_as_int(v), 0x111, 0xf, 0xf, false));
}
// xs = -log2e * x -> sigmoid(x) = 1/(1+2^xs)
__device__ __forceinline__ float sig_p(float xs) {
  return __builtin_amdgcn_rcpf(1.0f + EXP2F(xs));
}
// xt = 2*log2e * x -> tanh(x) = 1 - 2/(1+2^xt)
__device__ __forceinline__ float tanh_p(float xt) {
  return fmaf(-2.0f, __builtin_amdgcn_rcpf(1.0f + EXP2F(xt)), 1.0f);
}

// One pipeline tick for TWO independent chains (separate batch elements).
// pre0/pre1 are gate bases already in registers (pre-scaled). c is scaled.
template <bool GATED>
__device__ __forceinline__ void tick2(float& h0, float& c0, float& h1,
                                      float& c1, const float4 pre0,
                                      const float4 pre1, const float4 wih,
                                      const float4 whh, unsigned tau,
                                      unsigned lg) {
  const float hin0 = dpp_shr1(h0);
  const float hin1 = dpp_shr1(h1);
  const float a0 = fmaf(h0, whh.x, fmaf(hin0, wih.x, pre0.x));  // i
  const float b0 = fmaf(h1, whh.x, fmaf(hin1, wih.x, pre1.x));
  const float a1 = fmaf(h0, whh.y, fmaf(hin0, wih.y, pre0.y));  // f
  const float b1 = fmaf(h1, whh.y, fmaf(hin1, wih.y, pre1.y));
  const float a2 = fmaf(h0, whh.z, fmaf(hin0, wih.z, pre0.z));  // g
  const float b2 = fmaf(h1, whh.z, fmaf(hin1, wih.z, pre1.z));
  const float a3 = fmaf(h0, whh.w, fmaf(hin0, wih.w, pre0.w));  // o
  const float b3 = fmaf(h1, whh.w, fmaf(hin1, wih.w, pre1.w));
  const float i0 = sig_p(a0), i1 = sig_p(b0);
  const float f0 = sig_p(a1), f1 = sig_p(b1);
  const float g0 = tanh_p(a2), g1 = tanh_p(b2);
  const float o0 = sig_p(a3), o1 = sig_p(b3);
  const float is0 = P2L2E * i0;  // fold c-scale into i (off critical path)
  const float is1 = P2L2E * i1;
  const float cn0 = fmaf(f0, c0, is0 * g0);  // scaled cell
  const float cn1 = fmaf(f1, c1, is1 * g1);
  const float t0 = fmaf(-2.0f, __builtin_amdgcn_rcpf(1.0f + EXP2F(cn0)), 1.0f);
  const float t1 = fmaf(-2.0f, __builtin_amdgcn_rcpf(1.0f + EXP2F(cn1)), 1.0f);
  const float hn0 = o0 * t0;
  const float hn1 = o1 * t1;
  if (GATED) {
    const bool act = (tau - lg) < (unsigned)Tn;  // unsigned wrap: tau<lg off
    c0 = act ? cn0 : c0;  h0 = act ? hn0 : h0;
    c1 = act ? cn1 : c1;  h1 = act ? hn1 : h1;
  } else {
    c0 = cn0; h0 = hn0;
    c1 = cn1; h1 = hn1;
  }
}

// Fused: layer-0 projection (streaming x) + 6-layer DPP-pipelined recurrence.
// One wave per block; wave owns 16 batch elements = 2 independent chains per
// lane (elem ge and ge+8) for in-wave ILP. Grid = 256 -> 1 wave per CU.
__global__ __launch_bounds__(64, 1) void lstm_fused_kernel(
    const float* __restrict__ x, const float* __restrict__ w_ih0,
    const float* __restrict__ w_ih_rest, const float* __restrict__ w_hh,
    const float* __restrict__ b_ih, const float* __restrict__ b_hh,
    float* __restrict__ out) {
  __shared__ __align__(16) float4 bufA[CH * 16];  // [t_local][elem 0..15]
  __shared__ __align__(16) float4 bufB[CH * 16];

  const int ln = threadIdx.x;
  const int bW = blockIdx.x * 16;  // wave's batch base
  // tick-phase roles
  const int ge = ln >> 3;          // group 0..7 (chain0=ge, chain1=ge+8)
  const unsigned lg = ln & 7;      // pipeline lane = layer for lg<6
  const bool is0l = (lg == 0);
  // proj-phase roles
  const int ep = ln & 15;          // element 0..15
  const int t4 = ln >> 4;          // t sub-index 0..3

  // ---- per-lane recurrence weights (pre-scaled) ----
  const int l = (lg < 6) ? (int)lg : 5;
  float4 whh = make_float4(NL2E * w_hh[l * 4 + 0], NL2E * w_hh[l * 4 + 1],
                           P2L2E * w_hh[l * 4 + 2], NL2E * w_hh[l * 4 + 3]);
  float4 wih = make_float4(0.f, 0.f, 0.f, 0.f);
  float4 bz = make_float4(0.f, 0.f, 0.f, 0.f);  // non-leader gate bias (scaled)
  if (lg >= 1 && lg < 6) {
    wih = make_float4(NL2E * w_ih_rest[(l - 1) * 4 + 0],
                      NL2E * w_ih_rest[(l - 1) * 4 + 1],
                      P2L2E * w_ih_rest[(l - 1) * 4 + 2],
                      NL2E * w_ih_rest[(l - 1) * 4 + 3]);
    bz = make_float4(NL2E * (b_ih[lg * 4 + 0] + b_hh[lg * 4 + 0]),
                     NL2E * (b_ih[lg * 4 + 1] + b_hh[lg * 4 + 1]),
                     P2L2E * (b_ih[lg * 4 + 2] + b_hh[lg * 4 + 2]),
                     NL2E * (b_ih[lg * 4 + 3] + b_hh[lg * 4 + 3]));
  }
  if (lg >= 6) whh = make_float4(0.f, 0.f, 0.f, 0.f);  // inert lanes
  const float selm = is0l ? 1.0f : 0.0f;  // fma-mask: pre = proj*selm + bz

  // ---- layer-0 projection weights (uniform -> scalar regs), pre-scaled ----
  float w[4][16], pb[4];
  {
    const float sc[4] = {NL2E, NL2E, P2L2E, NL2E};
#pragma unroll
    for (int g = 0; g < 4; ++g) {
      pb[g] = sc[g] * (b_ih[g] + b_hh[g]);
#pragma unroll
      for (int d = 0; d < 16; ++d) w[g][d] = sc[g] * w_ih0[g * 16 + d];
    }
  }

  const float4* x4 = (const float4*)x;
  float4 xs[16];
  float h0 = 0.f, c0 = 0.f, h1 = 0.f, c1 = 0.f;

  // load half-chunk hf of chunk ci: lane covers elem ep, t = t4 + 4k (k=0..3)
  auto LOADH = [&](int ci, int hf) {
    const size_t rowb =
        (size_t)(bW + ep) * Tn + (size_t)ci * CH + (size_t)(hf * 16 + t4);
#pragma unroll
    for (int k = 0; k < 4; ++k)
#pragma unroll
      for (int i = 0; i < 4; ++i)
        xs[k * 4 + i] = x4[(rowb + (size_t)(4 * k)) * 4 + i];
  };
  // project the half-chunk currently in xs into dst
  auto PROJH = [&](float4* dst, int hf) {
#pragma unroll
    for (int k = 0; k < 4; ++k) {
      float s0 = pb[0], s1 = pb[1], s2 = pb[2], s3 = pb[3];
#pragma unroll
      for (int i = 0; i < 4; ++i) {
        const float4 a = xs[k * 4 + i];
        s0 = fmaf(a.x, w[0][i * 4 + 0], s0); s0 = fmaf(a.y, w[0][i * 4 + 1], s0);
        s0 = fmaf(a.z, w[0][i * 4 + 2], s0); s0 = fmaf(a.w, w[0][i * 4 + 3], s0);
        s1 = fmaf(a.x, w[1][i * 4 + 0], s1); s1 = fmaf(a.y, w[1][i * 4 + 1], s1);
        s1 = fmaf(a.z, w[1][i * 4 + 2], s1); s1 = fmaf(a.w, w[1][i * 4 + 3], s1);
        s2 = fmaf(a.x, w[2][i * 4 + 0], s2); s2 = fmaf(a.y, w[2][i * 4 + 1], s2);
        s2 = fmaf(a.z, w[2][i * 4 + 2], s2); s2 = fmaf(a.w, w[2][i * 4 + 3], s2);
        s3 = fmaf(a.x, w[3][i * 4 + 0], s3); s3 = fmaf(a.y, w[3][i * 4 + 1], s3);
        s3 = fmaf(a.z, w[3][i * 4 + 2], s3); s3 = fmaf(a.w, w[3][i * 4 + 3], s3);
      }
      dst[(hf * 16 + t4 + 4 * k) * 16 + ep] = make_float4(s0, s1, s2, s3);
    }
  };
  // one 8-tick block: bulk LDS->reg (broadcast reads), fma-mask, 8 ticks x2
  auto blockT = [&](const float4* bufc, int jb) {
    float4 p0[8], p1[8];
#pragma unroll
    for (int k = 0; k < 8; ++k) p0[k] = bufc[(jb * 8 + k) * 16 + ge];
#pragma unroll
    for (int k = 0; k < 8; ++k) p1[k] = bufc[(jb * 8 + k) * 16 + ge + 8];
#pragma unroll
    for (int k = 0; k < 8; ++k) {
      p0[k].x = fmaf(p0[k].x, selm, bz.x);
      p0[k].y = fmaf(p0[k].y, selm, bz.y);
      p0[k].z = fmaf(p0[k].z, selm, bz.z);
      p0[k].w = fmaf(p0[k].w, selm, bz.w);
      p1[k].x = fmaf(p1[k].x, selm, bz.x);
      p1[k].y = fmaf(p1[k].y, selm, bz.y);
      p1[k].z = fmaf(p1[k].z, selm, bz.z);
      p1[k].w = fmaf(p1[k].w, selm, bz.w);
    }
#pragma unroll
    for (int k = 0; k < 8; ++k)
      tick2<false>(h0, c0, h1, c1, p0[k], p1[k], wih, whh, 0u, 0u);
  };
  auto blockTg = [&](const float4* bufc, int jb, unsigned tau0) {
    float4 p0[8], p1[8];
#pragma unroll
    for (int k = 0; k < 8; ++k) p0[k] = bufc[(jb * 8 + k) * 16 + ge];
#pragma unroll
    for (int k = 0; k < 8; ++k) p1[k] = bufc[(jb * 8 + k) * 16 + ge + 8];
#pragma unroll
    for (int k = 0; k < 8; ++k) {
      p0[k].x = fmaf(p0[k].x, selm, bz.x);
      p0[k].y = fmaf(p0[k].y, selm, bz.y);
      p0[k].z = fmaf(p0[k].z, selm, bz.z);
      p0[k].w = fmaf(p0[k].w, selm, bz.w);
      p1[k].x = fmaf(p1[k].x, selm, bz.x);
      p1[k].y = fmaf(p1[k].y, selm, bz.y);
      p1[k].z = fmaf(p1[k].z, selm, bz.z);
      p1[k].w = fmaf(p1[k].w, selm, bz.w);
    }
#pragma unroll
    for (int k = 0; k < 8; ++k)
      tick2<true>(h0, c0, h1, c1, p0[k], p1[k], wih, whh, tau0 + (unsigned)k,
                  lg);
  };

  // ---- prologue: chunk 0 -> bufA; xs ends holding (chunk1, half0) ----
  LOADH(0, 0);
  PROJH(bufA, 0);
  LOADH(0, 1);
  PROJH(bufA, 1);
  LOADH(1, 0);

  // ---- chunk 0: block 0 gated (pipeline fill), 1..3 clean ----
  blockTg(bufA, 0, 0u);
  PROJH(bufB, 0);   // consumes xs = (1,0)
  blockT(bufA, 1);
  LOADH(1, 1);
  blockT(bufA, 2);
  PROJH(bufB, 1);   // consumes xs = (1,1)
  blockT(bufA, 3);
  LOADH(2, 0);

  // ---- chunks 1..15 (steady state: xs holds (j+1, 0) at entry) ----
#pragma unroll 1
  for (int j = 1; j < NCH; ++j) {
    const float4* bc = (j & 1) ? bufB : bufA;
    float4* bn = (j & 1) ? bufA : bufB;
    blockT(bc, 0);
    if (j < NCH - 1) PROJH(bn, 0);
    blockT(bc, 1);
    if (j < NCH - 1) LOADH(j + 1, 1);
    blockT(bc, 2);
    if (j < NCH - 1) PROJH(bn, 1);
    blockT(bc, 3);
    if (j < NCH - 2) LOADH(j + 2, 0);
  }

  // ---- tail: 5 gated ticks (tau=512..516); leaders inactive, pre=bz ----
#pragma unroll
  for (unsigned k = 0; k < 5; ++k)
    tick2<true>(h0, c0, h1, c1, bz, bz, wih, whh, 512u + k, lg);

  if (lg == 5) {  // H=1: hidden channel 0 == h
    out[bW + ge] = h0;
    out[bW + ge + 8] = h1;
  }
}

extern "C" void kernel_launch(void* const* d_in, const int* in_sizes, int n_in,
                              void* d_out, int out_size, void* d_ws, size_t ws_size,
                              hipStream_t stream) {
  (void)in_sizes; (void)n_in; (void)out_size; (void)d_ws; (void)ws_size;
  const float* x         = (const float*)d_in[0];
  const float* w_ih0     = (const float*)d_in[1];
  const float* w_ih_rest = (const float*)d_in[2];
  const float* w_hh      = (const float*)d_in[3];
  const float* b_ih      = (const float*)d_in[4];
  const float* b_hh      = (const float*)d_in[5];
  float* out = (float*)d_out;

  lstm_fused_kernel<<<Bn / 16, 64, 0, stream>>>(x, w_ih0, w_ih_rest, w_hh,
                                                b_ih, b_hh, out);
}

// Round 7
// 59.343 us; speedup vs baseline: 1.7255x; 1.7255x over previous
//
#include <hip/hip_runtime.h>

constexpr int Tn = 512;       // seq len
constexpr int Bn = 4096;      // batch
constexpr int CH = 32;        // timesteps per chunk
constexpr int NCH = Tn / CH;  // 16

// Gates are computed PRE-SCALED by folding these into weights/biases:
// i,f,o by -log2e (sigmoid), g by +2*log2e (tanh). Cell state c is carried
// scaled by +2*log2e so exp2(c_s) needs no multiply.
constexpr float NL2E = -1.44269504088896340736f;
constexpr float P2L2E = 2.88539008177792681472f;

#if defined(__has_builtin)
#if __has_builtin(__builtin_amdgcn_exp2f)
#define EXP2F(x) __builtin_amdgcn_exp2f(x)
#else
#define EXP2F(x) exp2f(x)
#endif
#else
#define EXP2F(x) exp2f(x)
#endif

// row_shr:1 within 16-lane rows: dst[i] = src[i-1]; lane0 of row keeps old.
__device__ __forceinline__ float dpp_shr1(float v) {
  return __int_as_float(__builtin_amdgcn_update_dpp(
      __float_as_int(v), __float_as_int(v), 0x111, 0xf, 0xf, false));
}

// One LSTM pipeline tick, shared-denominator form: 5 exp2 + 2 rcp.
//   sig(z)=1/(1+E), E=2^(-l2e*z); tanh(z)=(E-1)/(E+1), E=2^(2*l2e*z)
//   c' = sig(f)*c + sig(i)*tanh(g) = [c_s*P + 2l2e*(Eg-1)*Q] / (Q*P)  (scaled)
//   h  = sig(o)*tanh(c) = (Ec-1) / ((1+Eo)*(1+Ec)),  Ec = 2^(c_s)
template <bool GATED>
__device__ __forceinline__ void tick(float& h, float& c, const float4 pre,
                                     const float4 wih, const float4 whh,
                                     unsigned tau, unsigned lg) {
  const float h_in = dpp_shr1(h);
  const float ai = fmaf(h, whh.x, fmaf(h_in, wih.x, pre.x));  // -l2e * z_i
  const float af = fmaf(h, whh.y, fmaf(h_in, wih.y, pre.y));  // -l2e * z_f
  const float ag = fmaf(h, whh.z, fmaf(h_in, wih.z, pre.z));  // 2l2e * z_g
  const float ao = fmaf(h, whh.w, fmaf(h_in, wih.w, pre.w));  // -l2e * z_o
  const float Ei = EXP2F(ai);
  const float Ef = EXP2F(af);
  const float Eg = EXP2F(ag);
  const float Eo = EXP2F(ao);
  const float u = 1.0f + Ei;
  const float Q = 1.0f + Ef;
  const float v = 1.0f + Eg;
  const float P = u * v;
  const float QP = Q * P;
  const float ws = fmaf(P2L2E, Eg, -P2L2E);  // 2l2e*(Eg-1)
  const float num = fmaf(c, P, ws * Q);
  const float R = __builtin_amdgcn_rcpf(QP);
  const float cn = num * R;                   // new scaled cell
  const float Ec = EXP2F(fminf(cn, 80.0f));   // clamp: keep products finite
  const float so = 1.0f + Eo;
  const float t2 = 1.0f + Ec;
  const float R2 = __builtin_amdgcn_rcpf(so * t2);
  const float hn = (Ec - 1.0f) * R2;
  if (GATED) {
    const bool act = (tau - lg) < (unsigned)Tn;  // unsigned wrap: tau<lg off
    c = act ? cn : c;
    h = act ? hn : h;
  } else {
    c = cn;
    h = hn;
  }
}

// Fused: layer-0 projection (streaming x) + 6-layer DPP-pipelined recurrence.
// 512 single-wave blocks (2 blocks/CU -> 2 SIMDs busy per CU). Projection
// tiles double-buffered in LDS; per-8-tick register prefetch (pA/pB).
__global__ __launch_bounds__(64, 1) void lstm_fused_kernel(
    const float* __restrict__ x, const float* __restrict__ w_ih0,
    const float* __restrict__ w_ih_rest, const float* __restrict__ w_hh,
    const float* __restrict__ b_ih, const float* __restrict__ b_hh,
    float* __restrict__ out) {
  __shared__ __align__(16) float4 bufA[CH * 8];  // [t_local][elem]
  __shared__ __align__(16) float4 bufB[CH * 8];

  const int ln = threadIdx.x;
  const int bW = blockIdx.x * 8;  // wave's batch base
  // tick-phase roles
  const int ge = ln >> 3;         // batch element (group) 0..7
  const unsigned lg = ln & 7;     // pipeline lane = layer for lg<6
  const bool is0l = (lg == 0);
  // proj-phase roles
  const int ep = ln & 7;          // element
  const int t8p = ln >> 3;        // t sub-index 0..7

  // ---- per-lane recurrence weights (pre-scaled) ----
  const int l = (lg < 6) ? (int)lg : 5;
  float4 whh = make_float4(NL2E * w_hh[l * 4 + 0], NL2E * w_hh[l * 4 + 1],
                           P2L2E * w_hh[l * 4 + 2], NL2E * w_hh[l * 4 + 3]);
  float4 wih = make_float4(0.f, 0.f, 0.f, 0.f);
  float4 bz = make_float4(0.f, 0.f, 0.f, 0.f);  // non-leader gate bias (scaled)
  if (lg >= 1 && lg < 6) {
    wih = make_float4(NL2E * w_ih_rest[(l - 1) * 4 + 0],
                      NL2E * w_ih_rest[(l - 1) * 4 + 1],
                      P2L2E * w_ih_rest[(l - 1) * 4 + 2],
                      NL2E * w_ih_rest[(l - 1) * 4 + 3]);
    bz = make_float4(NL2E * (b_ih[lg * 4 + 0] + b_hh[lg * 4 + 0]),
                     NL2E * (b_ih[lg * 4 + 1] + b_hh[lg * 4 + 1]),
                     P2L2E * (b_ih[lg * 4 + 2] + b_hh[lg * 4 + 2]),
                     NL2E * (b_ih[lg * 4 + 3] + b_hh[lg * 4 + 3]));
  }
  if (lg >= 6) whh = make_float4(0.f, 0.f, 0.f, 0.f);  // inert lanes
  const float selm = is0l ? 1.0f : 0.0f;  // fma-mask: pre = proj*selm + bz

  // ---- layer-0 projection weights (uniform -> scalar regs), pre-scaled ----
  float w[4][16], pb[4];
  {
    const float sc[4] = {NL2E, NL2E, P2L2E, NL2E};
#pragma unroll
    for (int g = 0; g < 4; ++g) {
      pb[g] = sc[g] * (b_ih[g] + b_hh[g]);
#pragma unroll
      for (int d = 0; d < 16; ++d) w[g][d] = sc[g] * w_ih0[g * 16 + d];
    }
  }

  const float4* x4 = (const float4*)x;
  float4 xs[16];
  float h = 0.f, c = 0.f;
  float4 pA[8], pB[8];

  // lane reads 64 B of x for (bW+ep, t = ci*CH + t8p + 8k), k=0..3
  auto LOADC = [&](int ci) {
    const size_t base = ((size_t)(bW + ep) * Tn + (size_t)ci * CH + t8p) * 4;
#pragma unroll
    for (int k = 0; k < 4; ++k)
#pragma unroll
      for (int i = 0; i < 4; ++i) xs[k * 4 + i] = x4[base + (size_t)k * 32 + i];
  };
  // projection quarter k: t = t8p + 8k of the chunk in xs
  auto PROJq = [&](float4* dst, int k) {
    float s0 = pb[0], s1 = pb[1], s2 = pb[2], s3 = pb[3];
#pragma unroll
    for (int i = 0; i < 4; ++i) {
      const float4 a = xs[k * 4 + i];
      s0 = fmaf(a.x, w[0][i * 4 + 0], s0); s0 = fmaf(a.y, w[0][i * 4 + 1], s0);
      s0 = fmaf(a.z, w[0][i * 4 + 2], s0); s0 = fmaf(a.w, w[0][i * 4 + 3], s0);
      s1 = fmaf(a.x, w[1][i * 4 + 0], s1); s1 = fmaf(a.y, w[1][i * 4 + 1], s1);
      s1 = fmaf(a.z, w[1][i * 4 + 2], s1); s1 = fmaf(a.w, w[1][i * 4 + 3], s1);
      s2 = fmaf(a.x, w[2][i * 4 + 0], s2); s2 = fmaf(a.y, w[2][i * 4 + 1], s2);
      s2 = fmaf(a.z, w[2][i * 4 + 2], s2); s2 = fmaf(a.w, w[2][i * 4 + 3], s2);
      s3 = fmaf(a.x, w[3][i * 4 + 0], s3); s3 = fmaf(a.y, w[3][i * 4 + 1], s3);
      s3 = fmaf(a.z, w[3][i * 4 + 2], s3); s3 = fmaf(a.w, w[3][i * 4 + 3], s3);
    }
    dst[ln + 64 * k] = make_float4(s0, s1, s2, s3);  // [(t8p+8k)*8 + ep]
  };
  // bulk LDS->reg for one 8-tick block (8 broadcast ds_read_b128)
  auto RD = [&](float4* p, const float4* bufc, int jb) {
#pragma unroll
    for (int k = 0; k < 8; ++k) p[k] = bufc[(jb * 8 + k) * 8 + ge];
  };
  // 8 clean ticks consuming p (mask applied off critical path)
  auto T = [&](float4* p) {
    float4 q[8];
#pragma unroll
    for (int k = 0; k < 8; ++k) {
      q[k].x = fmaf(p[k].x, selm, bz.x);
      q[k].y = fmaf(p[k].y, selm, bz.y);
      q[k].z = fmaf(p[k].z, selm, bz.z);
      q[k].w = fmaf(p[k].w, selm, bz.w);
    }
#pragma unroll
    for (int k = 0; k < 8; ++k) tick<false>(h, c, q[k], wih, whh, 0u, 0u);
  };
  auto Tg = [&](float4* p, unsigned tau0) {
    float4 q[8];
#pragma unroll
    for (int k = 0; k < 8; ++k) {
      q[k].x = fmaf(p[k].x, selm, bz.x);
      q[k].y = fmaf(p[k].y, selm, bz.y);
      q[k].z = fmaf(p[k].z, selm, bz.z);
      q[k].w = fmaf(p[k].w, selm, bz.w);
    }
#pragma unroll
    for (int k = 0; k < 8; ++k)
      tick<true>(h, c, q[k], wih, whh, tau0 + (unsigned)k, lg);
  };

  // ---- prologue: chunk 0 -> bufA; chunk 1 x in regs; block0 in pA ----
  LOADC(0);
#pragma unroll
  for (int k = 0; k < 4; ++k) PROJq(bufA, k);
  LOADC(1);
  RD(pA, bufA, 0);

  // ---- chunk 0 (block 0 gated for pipeline fill) ----
  RD(pB, bufA, 1);  Tg(pA, 0u);
  RD(pA, bufA, 2);  T(pB);
  PROJq(bufB, 0);  PROJq(bufB, 1);
  RD(pB, bufA, 3);  T(pA);
  PROJq(bufB, 2);  PROJq(bufB, 3);
  RD(pA, bufB, 0);  T(pB);
  LOADC(2);

  // ---- chunks 1..15 (entry invariant: pA holds block 0 of chunk j) ----
#pragma unroll 1
  for (int j = 1; j < NCH; ++j) {
    const float4* bc = (j & 1) ? bufB : bufA;
    float4* bn = (j & 1) ? bufA : bufB;
    RD(pB, bc, 1);  T(pA);
    RD(pA, bc, 2);  T(pB);
    if (j < NCH - 1) { PROJq(bn, 0); PROJq(bn, 1); }
    RD(pB, bc, 3);  T(pA);
    if (j < NCH - 1) { PROJq(bn, 2); PROJq(bn, 3); }
    RD(pA, (j < NCH - 1) ? bn : bc, 0);  T(pB);
    if (j < NCH - 2) LOADC(j + 2);
  }

  // ---- tail: 5 gated ticks (tau=512..516); leaders inactive, pre=bz ----
#pragma unroll
  for (unsigned k = 0; k < 5; ++k)
    tick<true>(h, c, bz, wih, whh, 512u + k, lg);

  if (lg == 5) out[bW + ge] = h;  // H=1: hidden channel 0 == h
}

extern "C" void kernel_launch(void* const* d_in, const int* in_sizes, int n_in,
                              void* d_out, int out_size, void* d_ws, size_t ws_size,
                              hipStream_t stream) {
  (void)in_sizes; (void)n_in; (void)out_size; (void)d_ws; (void)ws_size;
  const float* x         = (const float*)d_in[0];
  const float* w_ih0     = (const float*)d_in[1];
  const float* w_ih_rest = (const float*)d_in[2];
  const float* w_hh      = (const float*)d_in[3];
  const float* b_ih      = (const float*)d_in[4];
  const float* b_hh      = (const float*)d_in[5];
  float* out = (float*)d_out;

  lstm_fused_kernel<<<Bn / 8, 64, 0, stream>>>(x, w_ih0, w_ih_rest, w_hh,
                                               b_ih, b_hh, out);
}